// Round 2
// baseline (449.487 us; speedup 1.0000x reference)
//
#include <hip/hip_runtime.h>

// ---------------------------------------------------------------------------
// SelfAttention: out = softmax((Q K^T + bias)/sqrt(E)) V, with projections.
// L=2048, E=1024, H=16, D=64. Inputs/outputs fp32; MFMA compute in bf16 with
// fp32 accumulate (f32->bf16 RNE conversion fused into LDS staging).
// Pipeline: [gemm_bt3 z=3: Q/K/V proj] -> [flash attention] -> [gemm_bt3 + bias]
// ---------------------------------------------------------------------------

#define L_SEQ 2048
#define E_DIM 1024
#define H_HEADS 16
#define D_HEAD 64

typedef unsigned short u16;
typedef __attribute__((ext_vector_type(8))) short bf16x8;     // 8 bf16 = 4 VGPRs
typedef __attribute__((ext_vector_type(8))) unsigned short u16x8;
typedef __attribute__((ext_vector_type(4))) unsigned short u16x4;
typedef __attribute__((ext_vector_type(4))) float f32x4;

__device__ __forceinline__ float bf2f(u16 u) {
  union { unsigned int i; float f; } v; v.i = ((unsigned int)u) << 16; return v.f;
}
__device__ __forceinline__ u16 f2bf(float f) {
  union { float f; unsigned int i; } v; v.f = f;
  unsigned int u = v.i;
  u += 0x7FFFu + ((u >> 16) & 1u);   // round-to-nearest-even
  return (u16)(u >> 16);
}

// ---------------------------------------------------------------------------
// NT GEMM: C[M,N] = A[M,K] * B[N,K]^T (+ bias[N]).  A,B fp32 in (converted to
// bf16 during staging), fp32 MFMA accumulate. CMODE: 0 = bf16 out, 1 = f32 out.
// 128x128 tile, BK=32, 256 threads (4 waves), each wave 64x64 (4x4 MFMA tiles).
// blockIdx.z selects one of three (A,B,C) triples (for fused QKV projection).
// ---------------------------------------------------------------------------
#define TM 128
#define TN 128
#define BK 32
#define LDK 40   // 32 + 8 pad: row stride 80B = 16B-aligned, spreads banks

template<int CMODE>
__global__ __launch_bounds__(256, 2) void gemm_bt3(
    const float* __restrict__ A0, const float* __restrict__ B0, void* __restrict__ C0,
    const float* __restrict__ A1, const float* __restrict__ B1, void* __restrict__ C1,
    const float* __restrict__ A2, const float* __restrict__ B2, void* __restrict__ C2,
    const float* __restrict__ bias, int M, int N, int K)
{
  const float* A; const float* B; void* C;
  if (blockIdx.z == 0)      { A = A0; B = B0; C = C0; }
  else if (blockIdx.z == 1) { A = A1; B = B1; C = C1; }
  else                      { A = A2; B = B2; C = C2; }

  __shared__ __align__(16) u16 As[TM][LDK];
  __shared__ __align__(16) u16 Bs[TN][LDK];

  const int m0 = blockIdx.y * TM;
  const int n0 = blockIdx.x * TN;
  const int t = threadIdx.x;
  const int wave = t >> 6;
  const int lane = t & 63;
  const int quad = lane >> 4;
  const int col  = lane & 15;
  const int wm = (wave >> 1) * 64;
  const int wn = (wave & 1) * 64;

  f32x4 acc[4][4];
#pragma unroll
  for (int i = 0; i < 4; ++i)
#pragma unroll
    for (int j = 0; j < 4; ++j) acc[i][j] = (f32x4){0.f, 0.f, 0.f, 0.f};

  for (int k0 = 0; k0 < K; k0 += BK) {
    __syncthreads();
    // stage A-tile and B-tile (128x32 f32 each -> bf16 in LDS)
#pragma unroll
    for (int s = 0; s < 4; ++s) {
      int idx = t + s * 256;        // 0..1023
      int r  = idx >> 3;            // 0..127
      int c4 = (idx & 7) * 4;       // 0,4,...,28
      f32x4 va = *(const f32x4*)&A[(size_t)(m0 + r) * K + k0 + c4];
      f32x4 vb = *(const f32x4*)&B[(size_t)(n0 + r) * K + k0 + c4];
      u16x4 pa, pb;
#pragma unroll
      for (int j = 0; j < 4; ++j) { pa[j] = f2bf(va[j]); pb[j] = f2bf(vb[j]); }
      *(u16x4*)&As[r][c4] = pa;
      *(u16x4*)&Bs[r][c4] = pb;
    }
    __syncthreads();

    bf16x8 af[4], bfr[4];
#pragma unroll
    for (int i = 0; i < 4; ++i)
      af[i] = *(const bf16x8*)&As[wm + i * 16 + col][quad * 8];
#pragma unroll
    for (int j = 0; j < 4; ++j)
      bfr[j] = *(const bf16x8*)&Bs[wn + j * 16 + col][quad * 8];

#pragma unroll
    for (int i = 0; i < 4; ++i)
#pragma unroll
      for (int j = 0; j < 4; ++j)
        acc[i][j] = __builtin_amdgcn_mfma_f32_16x16x32_bf16(af[i], bfr[j], acc[i][j], 0, 0, 0);
  }

  // epilogue: C/D layout col=lane&15, row=quad*4+reg
#pragma unroll
  for (int i = 0; i < 4; ++i) {
    int rowb = m0 + wm + i * 16 + quad * 4;
#pragma unroll
    for (int j = 0; j < 4; ++j) {
      int cn = n0 + wn + j * 16 + col;
      float badd = bias ? bias[cn] : 0.f;
#pragma unroll
      for (int r = 0; r < 4; ++r) {
        float val = acc[i][j][r] + badd;
        size_t off = (size_t)(rowb + r) * N + cn;
        if (CMODE == 0) ((u16*)C)[off] = f2bf(val);
        else            ((float*)C)[off] = val;
      }
    }
  }
}

// ---------------------------------------------------------------------------
// Flash attention: one block = (head h, 64 q-rows). 256 threads = 4 waves,
// each wave owns 16 q-rows. Stream K/V in 64-wide tiles with online softmax.
// Q/K/V bf16 (from proj GEMMs); dist fp32; output AO fp32.
// Q frags in registers; K staged [l][d]; V staged transposed [d][l]; P via LDS.
// ---------------------------------------------------------------------------
#define FK 64
#define LDV 72   // 64 + 8 pad: row stride 144B = 16B-aligned

__global__ __launch_bounds__(256, 2) void flash_attn(
    const u16* __restrict__ Q, const u16* __restrict__ Kp,
    const u16* __restrict__ Vp, const float* __restrict__ dist,
    float* __restrict__ AO)
{
  __shared__ __align__(16) u16 Ks[FK][LDV];      // K-tile: [k-row][d]
  __shared__ __align__(16) u16 Vs[D_HEAD][LDV];  // V-tile transposed: [d][l]
  __shared__ __align__(16) u16 Ps[4][16][LDV];   // per-wave P strip [row][l]

  const int h  = blockIdx.y;
  const int q0 = blockIdx.x * 64;
  const int hoff = h * D_HEAD;
  const int t = threadIdx.x;
  const int wave = t >> 6;
  const int lane = t & 63;
  const int quad = lane >> 4;
  const int col  = lane & 15;

  // Q fragments (A-operand layout): row = q0 + wave*16 + col, k = kk*32+quad*8+j
  bf16x8 qf[2];
  {
    const u16* qrow = Q + (size_t)(q0 + wave * 16 + col) * E_DIM + hoff;
    qf[0] = *(const bf16x8*)(qrow + quad * 8);
    qf[1] = *(const bf16x8*)(qrow + 32 + quad * 8);
  }

  float m_run[4], l_run[4];
  f32x4 oacc[4];
#pragma unroll
  for (int r = 0; r < 4; ++r) { m_run[r] = -INFINITY; l_run[r] = 0.f; }
#pragma unroll
  for (int td = 0; td < 4; ++td) oacc[td] = (f32x4){0.f, 0.f, 0.f, 0.f};

  const int qrow_mine = q0 + wave * 16 + quad * 4;  // +r for reg r

  for (int k0 = 0; k0 < L_SEQ; k0 += FK) {
    __syncthreads();   // previous iter's frag reads done before restage
    {
      int c = t & 7, r0 = t >> 3;   // c: 8-col chunk, r0: 0..31
#pragma unroll
      for (int s = 0; s < 2; ++s) {
        int rr = r0 + s * 32;
        *(u16x8*)&Ks[rr][c * 8] = *(const u16x8*)&Kp[(size_t)(k0 + rr) * E_DIM + hoff + c * 8];
        u16x8 vv = *(const u16x8*)&Vp[(size_t)(k0 + rr) * E_DIM + hoff + c * 8];
#pragma unroll
        for (int j = 0; j < 8; ++j) Vs[c * 8 + j][rr] = vv[j];  // transpose
      }
    }
    __syncthreads();

    // S = Q K^T : wave's 16 rows x 64 cols (4 col-tiles, 2 k-steps each)
    f32x4 sacc[4];
#pragma unroll
    for (int tt = 0; tt < 4; ++tt) {
      f32x4 a = (f32x4){0.f, 0.f, 0.f, 0.f};
      bf16x8 kf0 = *(const bf16x8*)&Ks[tt * 16 + col][quad * 8];
      a = __builtin_amdgcn_mfma_f32_16x16x32_bf16(qf[0], kf0, a, 0, 0, 0);
      bf16x8 kf1 = *(const bf16x8*)&Ks[tt * 16 + col][32 + quad * 8];
      a = __builtin_amdgcn_mfma_f32_16x16x32_bf16(qf[1], kf1, a, 0, 0, 0);
      sacc[tt] = a;
    }

    // logits = (qk + bias) / 32, bias = dist==0 ? 0 : 1/(dist+1)
    float sv[4][4];
#pragma unroll
    for (int tt = 0; tt < 4; ++tt) {
#pragma unroll
      for (int r = 0; r < 4; ++r) {
        float d = dist[(size_t)(qrow_mine + r) * L_SEQ + k0 + tt * 16 + col];
        float b = (d == 0.f) ? 0.f : 1.f / (d + 1.f);
        sv[tt][r] = (sacc[tt][r] + b) * 0.03125f;
      }
    }

    // row max over 64 cols: local over 4 tiles, then across 16 lanes of quad
    float mt[4];
#pragma unroll
    for (int r = 0; r < 4; ++r)
      mt[r] = fmaxf(fmaxf(sv[0][r], sv[1][r]), fmaxf(sv[2][r], sv[3][r]));
#pragma unroll
    for (int off = 1; off < 16; off <<= 1)
#pragma unroll
      for (int r = 0; r < 4; ++r) mt[r] = fmaxf(mt[r], __shfl_xor(mt[r], off));

    float alpha[4];
#pragma unroll
    for (int r = 0; r < 4; ++r) {
      float mn = fmaxf(m_run[r], mt[r]);
      alpha[r] = __expf(m_run[r] - mn);   // exp(-inf)=0 on first iter
      m_run[r] = mn;
    }

    // P = exp(s - m), row-sums, write P strip to LDS (bf16)
    float rs[4] = {0.f, 0.f, 0.f, 0.f};
#pragma unroll
    for (int tt = 0; tt < 4; ++tt) {
#pragma unroll
      for (int r = 0; r < 4; ++r) {
        float p = __expf(sv[tt][r] - m_run[r]);
        rs[r] += p;
        Ps[wave][quad * 4 + r][tt * 16 + col] = f2bf(p);
      }
    }
#pragma unroll
    for (int off = 1; off < 16; off <<= 1)
#pragma unroll
      for (int r = 0; r < 4; ++r) rs[r] += __shfl_xor(rs[r], off);
#pragma unroll
    for (int r = 0; r < 4; ++r) l_run[r] = l_run[r] * alpha[r] + rs[r];

    // rescale O accumulator
#pragma unroll
    for (int td = 0; td < 4; ++td)
#pragma unroll
      for (int r = 0; r < 4; ++r) oacc[td][r] *= alpha[r];

    __syncthreads();   // P strips visible / Vs reads ordered

    // O += P V : A = P strip (16x64), B = V (64x64) read from transposed Vs
#pragma unroll
    for (int kk = 0; kk < 2; ++kk) {
      bf16x8 pf = *(const bf16x8*)&Ps[wave][col][kk * 32 + quad * 8];
#pragma unroll
      for (int td = 0; td < 4; ++td) {
        bf16x8 vf = *(const bf16x8*)&Vs[td * 16 + col][kk * 32 + quad * 8];
        oacc[td] = __builtin_amdgcn_mfma_f32_16x16x32_bf16(pf, vf, oacc[td], 0, 0, 0);
      }
    }
  }

  // epilogue: normalize by l, write attn_out[q, h*64+d] as fp32
#pragma unroll
  for (int td = 0; td < 4; ++td) {
#pragma unroll
    for (int r = 0; r < 4; ++r) {
      float o = oacc[td][r] / l_run[r];
      AO[(size_t)(qrow_mine + r) * E_DIM + hoff + td * 16 + col] = o;
    }
  }
}

// ---------------------------------------------------------------------------
extern "C" void kernel_launch(void* const* d_in, const int* in_sizes, int n_in,
                              void* d_out, int out_size, void* d_ws, size_t ws_size,
                              hipStream_t stream)
{
  const float* values = (const float*)d_in[0];
  const float* keys   = (const float*)d_in[1];
  const float* query  = (const float*)d_in[2];
  const float* dist   = (const float*)d_in[3];
  const float* Wv     = (const float*)d_in[4];
  const float* Wk     = (const float*)d_in[5];
  const float* Wq     = (const float*)d_in[6];
  const float* Wo     = (const float*)d_in[7];
  const float* bo     = (const float*)d_in[8];
  float* out = (float*)d_out;

  const size_t SZ = (size_t)L_SEQ * E_DIM;   // 2M elems
  u16* Qb = (u16*)d_ws;                       // bf16 intermediates
  u16* Kb = Qb + SZ;
  u16* Vb = Qb + 2 * SZ;
  float* AO = (float*)(Qb + 3 * SZ);          // fp32 attention output

  // fused Q/K/V projections: z=0 -> Q, z=1 -> K, z=2 -> V (bf16 out)
  dim3 gProj(E_DIM / TN, L_SEQ / TM, 3);
  gemm_bt3<0><<<gProj, 256, 0, stream>>>(query,  Wq, Qb,
                                         keys,   Wk, Kb,
                                         values, Wv, Vb,
                                         nullptr, L_SEQ, E_DIM, E_DIM);

  dim3 gAttn(L_SEQ / 64, H_HEADS, 1);
  flash_attn<<<gAttn, 256, 0, stream>>>(Qb, Kb, Vb, dist, AO);

  // output projection + bias (f32 out)
  dim3 gOut(E_DIM / TN, L_SEQ / TM, 1);
  gemm_bt3<1><<<gOut, 256, 0, stream>>>(AO, Wo, out,
                                        AO, Wo, out,
                                        AO, Wo, out,
                                        bo, L_SEQ, E_DIM, E_DIM);
}

// Round 3
// 236.055 us; speedup vs baseline: 1.9042x; 1.9042x over previous
//
#include <hip/hip_runtime.h>

// ---------------------------------------------------------------------------
// SelfAttention, L=2048, E=1024, H=16, D=64. fp32 in/out, bf16 MFMA compute.
// Pipeline:
//   cvt_all     : f32->bf16 (q,k,v,Wq,Wk,Wv,Wo) + bias=1/(1+dist) as bf16[L][L]
//   gemm_bt3b<0>: Q,K,V projections (z=0,1,2); z=2 writes V^T [E][L]
//   flash2      : split-K flash attention (no-max softmax), partial O,l per split
//   merge_attn  : sum partials, divide, write bf16 AO
//   gemm_bt3b<1>: out = AO @ Wo^T + bo (f32 out)
// ---------------------------------------------------------------------------

#define L_SEQ 2048
#define E_DIM 1024
#define H_HEADS 16
#define D_HEAD 64
#define KSPLIT 4

typedef unsigned short u16;
typedef __attribute__((ext_vector_type(8))) short bf16x8;
typedef __attribute__((ext_vector_type(8))) unsigned short u16x8;
typedef __attribute__((ext_vector_type(4))) unsigned short u16x4;
typedef __attribute__((ext_vector_type(4))) float f32x4;

__device__ __forceinline__ float bf2f(u16 u) {
  union { unsigned int i; float f; } v; v.i = ((unsigned int)u) << 16; return v.f;
}
__device__ __forceinline__ u16 f2bf(float f) {
  union { float f; unsigned int i; } v; v.f = f;
  unsigned int u = v.i;
  u += 0x7FFFu + ((u >> 16) & 1u);   // RNE
  return (u16)(u >> 16);
}

// ---------------------------------------------------------------------------
// One-shot conversion: inputs+weights f32->bf16; bias = (d==0?0:1/(d+1)) bf16.
// Segment boundaries are multiples of 256 -> wave-uniform branches.
// ---------------------------------------------------------------------------
__global__ void cvt_all(const float* __restrict__ xq, const float* __restrict__ xk,
                        const float* __restrict__ xv,
                        const float* __restrict__ wq, const float* __restrict__ wk,
                        const float* __restrict__ wv, const float* __restrict__ wo,
                        const float* __restrict__ dist,
                        u16* oq, u16* ok, u16* ov,
                        u16* owq, u16* owk, u16* owv, u16* owo, u16* obias)
{
  size_t gid = (size_t)blockIdx.x * 256 + threadIdx.x;   // one f32x4 per thread
  const size_t NQ = 524288;   // (L*E)/4
  const size_t NW = 262144;   // (E*E)/4
  const float* src; u16* dst; size_t off; bool isb = false;
  if      (gid <     NQ)           { src = xq;   dst = oq;    off = gid; }
  else if (gid < 2 * NQ)           { src = xk;   dst = ok;    off = gid - NQ; }
  else if (gid < 3 * NQ)           { src = xv;   dst = ov;    off = gid - 2 * NQ; }
  else if (gid < 3 * NQ + NW)      { src = wq;   dst = owq;   off = gid - 3 * NQ; }
  else if (gid < 3 * NQ + 2 * NW)  { src = wk;   dst = owk;   off = gid - 3 * NQ - NW; }
  else if (gid < 3 * NQ + 3 * NW)  { src = wv;   dst = owv;   off = gid - 3 * NQ - 2 * NW; }
  else if (gid < 3 * NQ + 4 * NW)  { src = wo;   dst = owo;   off = gid - 3 * NQ - 3 * NW; }
  else { src = dist; dst = obias; off = gid - 3 * NQ - 4 * NW; isb = true; }

  f32x4 v = *(const f32x4*)&src[off * 4];
  u16x4 o;
#pragma unroll
  for (int j = 0; j < 4; ++j) {
    float f = v[j];
    if (isb) f = (f == 0.f) ? 0.f : 1.f / (f + 1.f);
    o[j] = f2bf(f);
  }
  *(u16x4*)&dst[off * 4] = o;
}

// ---------------------------------------------------------------------------
// NT GEMM, pure bf16: C[M,N] = A[M,K] * B[N,K]^T (+bias). 128x128, BK=32.
// OUTMODE 0: bf16 out; blockIdx.z==2 writes C^T (for V). OUTMODE 1: f32 +bias.
// ---------------------------------------------------------------------------
#define TM 128
#define TN 128
#define BK 32
#define LDK 40   // +8 pad, 80B rows (16B-aligned)

template<int OUTMODE>
__global__ __launch_bounds__(256, 2) void gemm_bt3b(
    const u16* __restrict__ A0, const u16* __restrict__ B0, void* __restrict__ C0,
    const u16* __restrict__ A1, const u16* __restrict__ B1, void* __restrict__ C1,
    const u16* __restrict__ A2, const u16* __restrict__ B2, void* __restrict__ C2,
    const float* __restrict__ bias, int M, int N, int K)
{
  const u16* A; const u16* B; void* C;
  if (blockIdx.z == 0)      { A = A0; B = B0; C = C0; }
  else if (blockIdx.z == 1) { A = A1; B = B1; C = C1; }
  else                      { A = A2; B = B2; C = C2; }

  __shared__ __align__(16) u16 As[TM][LDK];
  __shared__ __align__(16) u16 Bs[TN][LDK];

  const int m0 = blockIdx.y * TM;
  const int n0 = blockIdx.x * TN;
  const int t = threadIdx.x;
  const int wave = t >> 6;
  const int lane = t & 63;
  const int quad = lane >> 4;
  const int col  = lane & 15;
  const int wm = (wave >> 1) * 64;
  const int wn = (wave & 1) * 64;

  f32x4 acc[4][4];
#pragma unroll
  for (int i = 0; i < 4; ++i)
#pragma unroll
    for (int j = 0; j < 4; ++j) acc[i][j] = (f32x4){0.f, 0.f, 0.f, 0.f};

  for (int k0 = 0; k0 < K; k0 += BK) {
    __syncthreads();
#pragma unroll
    for (int s = 0; s < 2; ++s) {
      int idx = t + s * 256;        // 0..511
      int r  = idx >> 2;            // 0..127
      int c8 = (idx & 3) * 8;       // 0,8,16,24
      *(u16x8*)&As[r][c8] = *(const u16x8*)&A[(size_t)(m0 + r) * K + k0 + c8];
      *(u16x8*)&Bs[r][c8] = *(const u16x8*)&B[(size_t)(n0 + r) * K + k0 + c8];
    }
    __syncthreads();

    bf16x8 af[4], bfr[4];
#pragma unroll
    for (int i = 0; i < 4; ++i)
      af[i] = *(const bf16x8*)&As[wm + i * 16 + col][quad * 8];
#pragma unroll
    for (int j = 0; j < 4; ++j)
      bfr[j] = *(const bf16x8*)&Bs[wn + j * 16 + col][quad * 8];

#pragma unroll
    for (int i = 0; i < 4; ++i)
#pragma unroll
      for (int j = 0; j < 4; ++j)
        acc[i][j] = __builtin_amdgcn_mfma_f32_16x16x32_bf16(af[i], bfr[j], acc[i][j], 0, 0, 0);
  }

  const bool transC = (OUTMODE == 0) && (blockIdx.z == 2);
#pragma unroll
  for (int i = 0; i < 4; ++i) {
    int rowb = m0 + wm + i * 16 + quad * 4;
#pragma unroll
    for (int j = 0; j < 4; ++j) {
      int cn = n0 + wn + j * 16 + col;
      if (OUTMODE == 1) {
        float badd = bias ? bias[cn] : 0.f;
#pragma unroll
        for (int r = 0; r < 4; ++r)
          ((float*)C)[(size_t)(rowb + r) * N + cn] = acc[i][j][r] + badd;
      } else if (transC) {
        u16x4 pk;
#pragma unroll
        for (int r = 0; r < 4; ++r) pk[r] = f2bf(acc[i][j][r]);
        *(u16x4*)&((u16*)C)[(size_t)cn * M + rowb] = pk;   // C^T: 4 contiguous
      } else {
#pragma unroll
        for (int r = 0; r < 4; ++r)
          ((u16*)C)[(size_t)(rowb + r) * N + cn] = f2bf(acc[i][j][r]);
      }
    }
  }
}

// ---------------------------------------------------------------------------
// Split-K flash attention, no-max softmax (logits provably small: |s|<~25).
// Block = (64 q-rows, head h, split z). 4 waves x 16 q-rows. 8 k-tiles of 64.
// Writes unnormalized partial O (bf16) and partial l (f32) per split.
// ---------------------------------------------------------------------------
#define FK 64
#define LDV 72   // +8 pad, 144B rows

__global__ __launch_bounds__(256, 5) void flash2(
    const u16* __restrict__ Q, const u16* __restrict__ Kp,
    const u16* __restrict__ Vt, const u16* __restrict__ Bb,
    u16* __restrict__ Op, float* __restrict__ lp)
{
  __shared__ __align__(16) u16 Ks[FK][LDV];      // K-tile [l][d]
  __shared__ __align__(16) u16 Vs[D_HEAD][LDV];  // V^T tile [d][l]
  __shared__ __align__(16) u16 Ps[4][16][LDV];   // per-wave P strip [row][l]

  const int h  = blockIdx.y;
  const int q0 = blockIdx.x * 64;
  const int z  = blockIdx.z;
  const int hoff = h * D_HEAD;
  const int kbase = z * (L_SEQ / KSPLIT);        // 512-wide k range
  const int t = threadIdx.x;
  const int wave = t >> 6;
  const int lane = t & 63;
  const int quad = lane >> 4;
  const int col  = lane & 15;

  // Q fragments (A-layout): row = q0+wave*16+col, k = kk*32+quad*8+j
  bf16x8 qf[2];
  {
    const u16* qrow = Q + (size_t)(q0 + wave * 16 + col) * E_DIM + hoff;
    qf[0] = *(const bf16x8*)(qrow + quad * 8);
    qf[1] = *(const bf16x8*)(qrow + 32 + quad * 8);
  }

  float l_lane[4] = {0.f, 0.f, 0.f, 0.f};
  f32x4 oacc[4];
#pragma unroll
  for (int td = 0; td < 4; ++td) oacc[td] = (f32x4){0.f, 0.f, 0.f, 0.f};

  const int qrow_mine = q0 + wave * 16 + quad * 4;  // +r

  const int cst = t & 7, rst = t >> 3;   // staging: 8 chunks/row, 32 rows/pass
  for (int kt = 0; kt < L_SEQ / KSPLIT / FK; ++kt) {
    const int k0 = kbase + kt * FK;
    __syncthreads();   // prev PV reads done before restage
#pragma unroll
    for (int s = 0; s < 2; ++s) {
      int rr = rst + s * 32;
      *(u16x8*)&Ks[rr][cst * 8] = *(const u16x8*)&Kp[(size_t)(k0 + rr) * E_DIM + hoff + cst * 8];
      *(u16x8*)&Vs[rr][cst * 8] = *(const u16x8*)&Vt[(size_t)(hoff + rr) * L_SEQ + k0 + cst * 8];
    }
    // bias loads (independent of staging; scheduler overlaps)
    float bias_v[4][4];
#pragma unroll
    for (int tt = 0; tt < 4; ++tt)
#pragma unroll
      for (int r = 0; r < 4; ++r)
        bias_v[tt][r] = bf2f(Bb[(size_t)(qrow_mine + r) * L_SEQ + k0 + tt * 16 + col]);
    __syncthreads();

    // S = Q K^T (wave's 16 rows x 64 cols)
    f32x4 sacc[4];
#pragma unroll
    for (int tt = 0; tt < 4; ++tt) {
      f32x4 a = (f32x4){0.f, 0.f, 0.f, 0.f};
      a = __builtin_amdgcn_mfma_f32_16x16x32_bf16(qf[0], *(const bf16x8*)&Ks[tt * 16 + col][quad * 8], a, 0, 0, 0);
      a = __builtin_amdgcn_mfma_f32_16x16x32_bf16(qf[1], *(const bf16x8*)&Ks[tt * 16 + col][32 + quad * 8], a, 0, 0, 0);
      sacc[tt] = a;
    }

    // P = exp((s+bias)/32); accumulate per-lane row sums; store P strip
#pragma unroll
    for (int tt = 0; tt < 4; ++tt) {
#pragma unroll
      for (int r = 0; r < 4; ++r) {
        float p = __expf((sacc[tt][r] + bias_v[tt][r]) * 0.03125f);
        l_lane[r] += p;
        Ps[wave][quad * 4 + r][tt * 16 + col] = f2bf(p);
      }
    }
    // same-wave LDS RAW (P write -> P read): ordered by lgkmcnt, no barrier.

    // O += P V
#pragma unroll
    for (int kk = 0; kk < 2; ++kk) {
      bf16x8 pf = *(const bf16x8*)&Ps[wave][col][kk * 32 + quad * 8];
#pragma unroll
      for (int td = 0; td < 4; ++td) {
        bf16x8 vf = *(const bf16x8*)&Vs[td * 16 + col][kk * 32 + quad * 8];
        oacc[td] = __builtin_amdgcn_mfma_f32_16x16x32_bf16(pf, vf, oacc[td], 0, 0, 0);
      }
    }
  }

  // epilogue: reduce l across the 16 lanes of each quad-row group
#pragma unroll
  for (int off = 1; off < 16; off <<= 1)
#pragma unroll
    for (int r = 0; r < 4; ++r) l_lane[r] += __shfl_xor(l_lane[r], off);

#pragma unroll
  for (int td = 0; td < 4; ++td)
#pragma unroll
    for (int r = 0; r < 4; ++r)
      Op[((size_t)z * L_SEQ + qrow_mine + r) * E_DIM + hoff + td * 16 + col] = f2bf(oacc[td][r]);

  if (col == 0) {
#pragma unroll
    for (int r = 0; r < 4; ++r)
      lp[((size_t)z * L_SEQ + qrow_mine + r) * H_HEADS + h] = l_lane[r];
  }
}

// ---------------------------------------------------------------------------
// Merge split-K partials: AO = (sum_s O_s) / (sum_s l_s), bf16 out.
// ---------------------------------------------------------------------------
__global__ void merge_attn(const u16* __restrict__ Op, const float* __restrict__ lp,
                           u16* __restrict__ AOb)
{
  size_t gid = (size_t)blockIdx.x * 256 + threadIdx.x;  // one 4-elem group
  size_t idx = gid * 4;
  int q = (int)(idx >> 10);        // / E_DIM
  int e = (int)(idx & 1023);
  int h = e >> 6;
  float o[4] = {0.f, 0.f, 0.f, 0.f};
  float lsum = 0.f;
#pragma unroll
  for (int s = 0; s < KSPLIT; ++s) {
    u16x4 pv = *(const u16x4*)&Op[((size_t)s * L_SEQ + q) * E_DIM + e];
#pragma unroll
    for (int j = 0; j < 4; ++j) o[j] += bf2f(pv[j]);
    lsum += lp[((size_t)s * L_SEQ + q) * H_HEADS + h];
  }
  float inv = 1.f / lsum;
  u16x4 pk;
#pragma unroll
  for (int j = 0; j < 4; ++j) pk[j] = f2bf(o[j] * inv);
  *(u16x4*)&AOb[idx] = pk;
}

// ---------------------------------------------------------------------------
extern "C" void kernel_launch(void* const* d_in, const int* in_sizes, int n_in,
                              void* d_out, int out_size, void* d_ws, size_t ws_size,
                              hipStream_t stream)
{
  const float* values = (const float*)d_in[0];
  const float* keys   = (const float*)d_in[1];
  const float* query  = (const float*)d_in[2];
  const float* dist   = (const float*)d_in[3];
  const float* Wv     = (const float*)d_in[4];
  const float* Wk     = (const float*)d_in[5];
  const float* Wq     = (const float*)d_in[6];
  const float* Wo     = (const float*)d_in[7];
  const float* bo     = (const float*)d_in[8];
  float* out = (float*)d_out;

  const size_t MB = (size_t)1 << 20;
  char* w = (char*)d_ws;
  u16* xq  = (u16*)(w + 0 * MB);    // 4 MB  (dead after proj)
  u16* xk  = (u16*)(w + 4 * MB);    // 4 MB  (dead after proj)
  u16* xv  = (u16*)(w + 8 * MB);    // 4 MB  (dead after proj)
  u16* wqb = (u16*)(w + 12 * MB);   // 2 MB  (dead after proj)
  u16* wkb = (u16*)(w + 14 * MB);   // 2 MB  (dead after proj)
  u16* wvb = (u16*)(w + 16 * MB);   // 2 MB  (dead after proj)
  u16* wob = (u16*)(w + 18 * MB);   // 2 MB  (live to end)
  u16* Bb  = (u16*)(w + 20 * MB);   // 8 MB  bias bf16 [L][L]
  u16* Qh  = (u16*)(w + 28 * MB);   // 4 MB
  u16* Kh  = (u16*)(w + 32 * MB);   // 4 MB
  u16* Vth = (u16*)(w + 36 * MB);   // 4 MB  V^T [E][L]
  u16* AOb = (u16*)(w + 40 * MB);   // 4 MB
  float* lp = (float*)(w + 44 * MB);// 0.5 MB
  u16* Op  = (u16*)(w + 0 * MB);    // 16 MB, overlaps dead xq..wvb region

  // 1) convert inputs/weights to bf16 + precompute bias
  cvt_all<<<14336, 256, 0, stream>>>(query, keys, values, Wq, Wk, Wv, Wo, dist,
                                     xq, xk, xv, wqb, wkb, wvb, wob, Bb);

  // 2) Q/K/V projections (z=2 -> V^T)
  dim3 gProj(E_DIM / TN, L_SEQ / TM, 3);
  gemm_bt3b<0><<<gProj, 256, 0, stream>>>(xq, wqb, Qh,
                                          xk, wkb, Kh,
                                          xv, wvb, Vth,
                                          nullptr, L_SEQ, E_DIM, E_DIM);

  // 3) split-K flash attention
  dim3 gAttn(L_SEQ / 64, H_HEADS, KSPLIT);
  flash2<<<gAttn, 256, 0, stream>>>(Qh, Kh, Vth, Bb, Op, lp);

  // 4) merge partials -> bf16 AO
  merge_attn<<<(L_SEQ * E_DIM / 4) / 256, 256, 0, stream>>>(Op, lp, AOb);

  // 5) output projection + bias (f32 out)
  dim3 gOut(E_DIM / TN, L_SEQ / TM, 1);
  gemm_bt3b<1><<<gOut, 256, 0, stream>>>(AOb, wob, out,
                                         AOb, wob, out,
                                         AOb, wob, out,
                                         bo, L_SEQ, E_DIM, E_DIM);
}

// Round 4
// 218.217 us; speedup vs baseline: 2.0598x; 1.0817x over previous
//
#include <hip/hip_runtime.h>

// ---------------------------------------------------------------------------
// SelfAttention, L=2048, E=1024, H=16, D=64. fp32 in/out, bf16 MFMA compute.
//   cvt_all     : f32->bf16 (q,k,v,W*) + bias = (1/(1+dist))*log2e/32 as bf16
//   gemm_bt3b<0>: Q,K,V projections (z=2 writes V^T), global_load_lds staging
//   flash3      : split-K flash, S^T-form softmax (packed P writes), no-max
//   merge_attn  : sum partials, divide, write bf16 AO
//   gemm_bt3b<1>: out = AO @ Wo^T + bo (f32 out)
// ---------------------------------------------------------------------------

#define L_SEQ 2048
#define E_DIM 1024
#define H_HEADS 16
#define D_HEAD 64
#define KSPLIT 4

typedef unsigned short u16;
typedef unsigned int u32;
typedef __attribute__((ext_vector_type(8))) short bf16x8;
typedef __attribute__((ext_vector_type(8))) unsigned short u16x8;
typedef __attribute__((ext_vector_type(4))) unsigned short u16x4;
typedef __attribute__((ext_vector_type(4))) float f32x4;

#define C_LOG2E_32 0.045084220027780106f   // log2(e)/32

__device__ __forceinline__ float bf2f(u16 u) {
  union { u32 i; float f; } v; v.i = ((u32)u) << 16; return v.f;
}
__device__ __forceinline__ u16 f2bf(float f) {
  union { float f; u32 i; } v; v.f = f;
  u32 u = v.i;
  u += 0x7FFFu + ((u >> 16) & 1u);   // RNE
  return (u16)(u >> 16);
}
// pack bf16(lo), bf16(hi) into one u32 (round-half-up; p>0 so no edge cases)
__device__ __forceinline__ u32 pack_bf16_pair(float lo, float hi) {
  union { float f; u32 u; } a, b;
  a.f = lo; b.f = hi;
  return __builtin_amdgcn_perm(b.u + 0x8000u, a.u + 0x8000u, 0x07060302u);
}
// async global->LDS 16B per lane; LDS dest = (uniform base) + lane*16
__device__ __forceinline__ void gload16(const u16* g, u16* l) {
  __builtin_amdgcn_global_load_lds(
      (const __attribute__((address_space(1))) u32*)g,
      (__attribute__((address_space(3))) u32*)l, 16, 0, 0);
}

// ---------------------------------------------------------------------------
// One-shot conversion: inputs+weights f32->bf16; bias prescaled by log2e/32.
// ---------------------------------------------------------------------------
__global__ void cvt_all(const float* __restrict__ xq, const float* __restrict__ xk,
                        const float* __restrict__ xv,
                        const float* __restrict__ wq, const float* __restrict__ wk,
                        const float* __restrict__ wv, const float* __restrict__ wo,
                        const float* __restrict__ dist,
                        u16* oq, u16* ok, u16* ov,
                        u16* owq, u16* owk, u16* owv, u16* owo, u16* obias)
{
  size_t gid = (size_t)blockIdx.x * 256 + threadIdx.x;   // one f32x4 per thread
  const size_t NQ = 524288;   // (L*E)/4
  const size_t NW = 262144;   // (E*E)/4
  const float* src; u16* dst; size_t off; bool isb = false;
  if      (gid <     NQ)           { src = xq;   dst = oq;    off = gid; }
  else if (gid < 2 * NQ)           { src = xk;   dst = ok;    off = gid - NQ; }
  else if (gid < 3 * NQ)           { src = xv;   dst = ov;    off = gid - 2 * NQ; }
  else if (gid < 3 * NQ + NW)      { src = wq;   dst = owq;   off = gid - 3 * NQ; }
  else if (gid < 3 * NQ + 2 * NW)  { src = wk;   dst = owk;   off = gid - 3 * NQ - NW; }
  else if (gid < 3 * NQ + 3 * NW)  { src = wv;   dst = owv;   off = gid - 3 * NQ - 2 * NW; }
  else if (gid < 3 * NQ + 4 * NW)  { src = wo;   dst = owo;   off = gid - 3 * NQ - 3 * NW; }
  else { src = dist; dst = obias; off = gid - 3 * NQ - 4 * NW; isb = true; }

  f32x4 v = *(const f32x4*)&src[off * 4];
  u16x4 o;
#pragma unroll
  for (int j = 0; j < 4; ++j) {
    float f = v[j];
    if (isb) f = (f == 0.f) ? 0.f : C_LOG2E_32 / (f + 1.f);
    o[j] = f2bf(f);
  }
  *(u16x4*)&dst[off * 4] = o;
}

// ---------------------------------------------------------------------------
// NT GEMM, bf16, global_load_lds staging (unpadded LDS, m97 pattern).
// C[M,N] = A[M,K]*B[N,K]^T. 128x128 tile, BK=32, 4 waves of 64x64.
// OUTMODE 0: bf16 out; z==2 writes C^T. OUTMODE 1: f32 out + bias.
// ---------------------------------------------------------------------------
#define TM 128
#define TN 128
#define BK 32

template<int OUTMODE>
__global__ __launch_bounds__(256, 2) void gemm_bt3b(
    const u16* __restrict__ A0, const u16* __restrict__ B0, void* __restrict__ C0,
    const u16* __restrict__ A1, const u16* __restrict__ B1, void* __restrict__ C1,
    const u16* __restrict__ A2, const u16* __restrict__ B2, void* __restrict__ C2,
    const float* __restrict__ bias, int M, int N, int K)
{
  const u16* A; const u16* B; void* C;
  if (blockIdx.z == 0)      { A = A0; B = B0; C = C0; }
  else if (blockIdx.z == 1) { A = A1; B = B1; C = C1; }
  else                      { A = A2; B = B2; C = C2; }

  __shared__ __align__(16) u16 As[TM][BK];   // unpadded: global_load_lds layout
  __shared__ __align__(16) u16 Bs[TN][BK];

  const int m0 = blockIdx.y * TM;
  const int n0 = blockIdx.x * TN;
  const int t = threadIdx.x;
  const int wave = t >> 6;
  const int lane = t & 63;
  const int quad = lane >> 4;
  const int col  = lane & 15;
  const int wm = (wave >> 1) * 64;
  const int wn = (wave & 1) * 64;

  // staging map: instr covers 16 rows x 32 cols; lane -> row lane/4, col (lane&3)*8
  const int lr = lane >> 2;
  const int lc = (lane & 3) * 8;
  const u16* gA = A + (size_t)(m0 + wave * 32 + lr) * K + lc;
  const u16* gB = B + (size_t)(n0 + wave * 32 + lr) * K + lc;
  u16* lA0 = &As[wave * 32][0];
  u16* lA1 = &As[wave * 32 + 16][0];
  u16* lB0 = &Bs[wave * 32][0];
  u16* lB1 = &Bs[wave * 32 + 16][0];

  f32x4 acc[4][4];
#pragma unroll
  for (int i = 0; i < 4; ++i)
#pragma unroll
    for (int j = 0; j < 4; ++j) acc[i][j] = (f32x4){0.f, 0.f, 0.f, 0.f};

  for (int k0 = 0; k0 < K; k0 += BK) {
    __syncthreads();
    gload16(gA + k0, lA0);
    gload16(gA + (size_t)16 * K + k0, lA1);
    gload16(gB + k0, lB0);
    gload16(gB + (size_t)16 * K + k0, lB1);
    __syncthreads();   // drains vmcnt -> LDS data visible

    bf16x8 af[4], bfr[4];
#pragma unroll
    for (int i = 0; i < 4; ++i)
      af[i] = *(const bf16x8*)&As[wm + i * 16 + col][quad * 8];
#pragma unroll
    for (int j = 0; j < 4; ++j)
      bfr[j] = *(const bf16x8*)&Bs[wn + j * 16 + col][quad * 8];

#pragma unroll
    for (int i = 0; i < 4; ++i)
#pragma unroll
      for (int j = 0; j < 4; ++j)
        acc[i][j] = __builtin_amdgcn_mfma_f32_16x16x32_bf16(af[i], bfr[j], acc[i][j], 0, 0, 0);
  }

  const bool transC = (OUTMODE == 0) && (blockIdx.z == 2);
#pragma unroll
  for (int i = 0; i < 4; ++i) {
    int rowb = m0 + wm + i * 16 + quad * 4;
#pragma unroll
    for (int j = 0; j < 4; ++j) {
      int cn = n0 + wn + j * 16 + col;
      if (OUTMODE == 1) {
        float badd = bias ? bias[cn] : 0.f;
#pragma unroll
        for (int r = 0; r < 4; ++r)
          ((float*)C)[(size_t)(rowb + r) * N + cn] = acc[i][j][r] + badd;
      } else if (transC) {
        u16x4 pk;
#pragma unroll
        for (int r = 0; r < 4; ++r) pk[r] = f2bf(acc[i][j][r]);
        *(u16x4*)&((u16*)C)[(size_t)cn * M + rowb] = pk;   // C^T: 4 contiguous
      } else {
#pragma unroll
        for (int r = 0; r < 4; ++r)
          ((u16*)C)[(size_t)(rowb + r) * N + cn] = f2bf(acc[i][j][r]);
      }
    }
  }
}

// ---------------------------------------------------------------------------
// Split-K flash attention, S^T form: S^T = K Q^T gives each lane 4 contiguous
// l per tile -> packed b64 P writes + vectorized bias loads. No-max softmax
// (logit*log2e/32 bounded ~|1|; fp32 exp2 safe). Partial O (bf16) + l (f32).
// ---------------------------------------------------------------------------
#define FK 64
#define LDV 72   // +8 pad, 144B rows (16B-aligned)

__global__ __launch_bounds__(256, 5) void flash3(
    const u16* __restrict__ Q, const u16* __restrict__ Kp,
    const u16* __restrict__ Vt, const u16* __restrict__ Bb,
    u16* __restrict__ Op, float* __restrict__ lp)
{
  __shared__ __align__(16) u16 Ks[FK][LDV];      // K-tile [l][d]
  __shared__ __align__(16) u16 Vs[D_HEAD][LDV];  // V^T tile [d][l]
  __shared__ __align__(16) u16 Ps[4][16][LDV];   // per-wave P strip [q-row][l]

  const int h  = blockIdx.y;
  const int q0 = blockIdx.x * 64;
  const int z  = blockIdx.z;
  const int hoff = h * D_HEAD;
  const int kbase = z * (L_SEQ / KSPLIT);
  const int t = threadIdx.x;
  const int wave = t >> 6;
  const int lane = t & 63;
  const int quad = lane >> 4;
  const int col  = lane & 15;

  // Q fragments (B-operand: n = q = col, k = d = quad*8+j)
  bf16x8 qf[2];
  {
    const u16* qrow = Q + (size_t)(q0 + wave * 16 + col) * E_DIM + hoff;
    qf[0] = *(const bf16x8*)(qrow + quad * 8);
    qf[1] = *(const bf16x8*)(qrow + 32 + quad * 8);
  }

  float l_lane = 0.f;                 // partial row-sum for q = q0+wave*16+col
  f32x4 oacc[4];
#pragma unroll
  for (int td = 0; td < 4; ++td) oacc[td] = (f32x4){0.f, 0.f, 0.f, 0.f};

  const u16* brow = Bb + (size_t)(q0 + wave * 16 + col) * L_SEQ;  // prescaled bias
  const int cst = t & 7, rst = t >> 3;

  for (int kt = 0; kt < L_SEQ / KSPLIT / FK; ++kt) {
    const int k0 = kbase + kt * FK;
    __syncthreads();
#pragma unroll
    for (int s = 0; s < 2; ++s) {
      int rr = rst + s * 32;
      *(u16x8*)&Ks[rr][cst * 8] = *(const u16x8*)&Kp[(size_t)(k0 + rr) * E_DIM + hoff + cst * 8];
      *(u16x8*)&Vs[rr][cst * 8] = *(const u16x8*)&Vt[(size_t)(hoff + rr) * L_SEQ + k0 + cst * 8];
    }
    // bias (prescaled): lane needs l = tt*16+quad*4..+3 for its q -> 8B loads
    float pb[4][4];
#pragma unroll
    for (int tt = 0; tt < 4; ++tt) {
      u16x4 bv = *(const u16x4*)&brow[k0 + tt * 16 + quad * 4];
#pragma unroll
      for (int r = 0; r < 4; ++r) pb[tt][r] = bf2f(bv[r]);
    }
    __syncthreads();

    // S^T = K Q^T : A = K-frag (m=l), B = Q-frag (n=q). C/D: col=q, row=l.
#pragma unroll
    for (int tt = 0; tt < 4; ++tt) {
      f32x4 a = (f32x4){0.f, 0.f, 0.f, 0.f};
      a = __builtin_amdgcn_mfma_f32_16x16x32_bf16(*(const bf16x8*)&Ks[tt * 16 + col][quad * 8], qf[0], a, 0, 0, 0);
      a = __builtin_amdgcn_mfma_f32_16x16x32_bf16(*(const bf16x8*)&Ks[tt * 16 + col][32 + quad * 8], qf[1], a, 0, 0, 0);
      // p = 2^(s*c + bias*c); pack 4 contiguous l -> one b64 LDS write
      float p[4];
#pragma unroll
      for (int r = 0; r < 4; ++r) {
        p[r] = __builtin_amdgcn_exp2f(fmaf(a[r], C_LOG2E_32, pb[tt][r]));
        l_lane += p[r];
      }
      uint2 w;
      w.x = pack_bf16_pair(p[0], p[1]);
      w.y = pack_bf16_pair(p[2], p[3]);
      *(uint2*)&Ps[wave][col][tt * 16 + quad * 4] = w;   // P[q=col][l..l+3]
    }
    // same-wave LDS writes/reads are in-order: no barrier needed for Ps.

    // O += P V : A = P strip [q][l], B = V^T [d][l]
#pragma unroll
    for (int kk = 0; kk < 2; ++kk) {
      bf16x8 pf = *(const bf16x8*)&Ps[wave][col][kk * 32 + quad * 8];
#pragma unroll
      for (int td = 0; td < 4; ++td) {
        bf16x8 vf = *(const bf16x8*)&Vs[td * 16 + col][kk * 32 + quad * 8];
        oacc[td] = __builtin_amdgcn_mfma_f32_16x16x32_bf16(pf, vf, oacc[td], 0, 0, 0);
      }
    }
  }

  // l: lane holds partial for q=col over its quad's l values; sum across quads
  l_lane += __shfl_xor(l_lane, 16);
  l_lane += __shfl_xor(l_lane, 32);
  if (lane < 16)
    lp[((size_t)z * L_SEQ + q0 + wave * 16 + lane) * H_HEADS + h] = l_lane;

  const int qrow_mine = q0 + wave * 16 + quad * 4;
#pragma unroll
  for (int td = 0; td < 4; ++td)
#pragma unroll
    for (int r = 0; r < 4; ++r)
      Op[((size_t)z * L_SEQ + qrow_mine + r) * E_DIM + hoff + td * 16 + col] = f2bf(oacc[td][r]);
}

// ---------------------------------------------------------------------------
// Merge split-K partials: AO = (sum_s O_s) / (sum_s l_s), bf16 out.
// ---------------------------------------------------------------------------
__global__ void merge_attn(const u16* __restrict__ Op, const float* __restrict__ lp,
                           u16* __restrict__ AOb)
{
  size_t gid = (size_t)blockIdx.x * 256 + threadIdx.x;
  size_t idx = gid * 4;
  int q = (int)(idx >> 10);
  int e = (int)(idx & 1023);
  int h = e >> 6;
  float o[4] = {0.f, 0.f, 0.f, 0.f};
  float lsum = 0.f;
#pragma unroll
  for (int s = 0; s < KSPLIT; ++s) {
    u16x4 pv = *(const u16x4*)&Op[((size_t)s * L_SEQ + q) * E_DIM + e];
#pragma unroll
    for (int j = 0; j < 4; ++j) o[j] += bf2f(pv[j]);
    lsum += lp[((size_t)s * L_SEQ + q) * H_HEADS + h];
  }
  float inv = 1.f / lsum;
  u16x4 pk;
#pragma unroll
  for (int j = 0; j < 4; ++j) pk[j] = f2bf(o[j] * inv);
  *(u16x4*)&AOb[idx] = pk;
}

// ---------------------------------------------------------------------------
extern "C" void kernel_launch(void* const* d_in, const int* in_sizes, int n_in,
                              void* d_out, int out_size, void* d_ws, size_t ws_size,
                              hipStream_t stream)
{
  const float* values = (const float*)d_in[0];
  const float* keys   = (const float*)d_in[1];
  const float* query  = (const float*)d_in[2];
  const float* dist   = (const float*)d_in[3];
  const float* Wv     = (const float*)d_in[4];
  const float* Wk     = (const float*)d_in[5];
  const float* Wq     = (const float*)d_in[6];
  const float* Wo     = (const float*)d_in[7];
  const float* bo     = (const float*)d_in[8];
  float* out = (float*)d_out;

  const size_t MB = (size_t)1 << 20;
  char* w = (char*)d_ws;
  u16* xq  = (u16*)(w + 0 * MB);    // 4 MB  (dead after proj)
  u16* xk  = (u16*)(w + 4 * MB);    // 4 MB  (dead after proj)
  u16* xv  = (u16*)(w + 8 * MB);    // 4 MB  (dead after proj)
  u16* wqb = (u16*)(w + 12 * MB);   // 2 MB  (dead after proj)
  u16* wkb = (u16*)(w + 14 * MB);   // 2 MB  (dead after proj)
  u16* wvb = (u16*)(w + 16 * MB);   // 2 MB  (dead after proj)
  u16* wob = (u16*)(w + 18 * MB);   // 2 MB  (live to end)
  u16* Bb  = (u16*)(w + 20 * MB);   // 8 MB  prescaled bias bf16 [L][L]
  u16* Qh  = (u16*)(w + 28 * MB);   // 4 MB
  u16* Kh  = (u16*)(w + 32 * MB);   // 4 MB
  u16* Vth = (u16*)(w + 36 * MB);   // 4 MB  V^T [E][L]
  u16* AOb = (u16*)(w + 40 * MB);   // 4 MB
  float* lp = (float*)(w + 44 * MB);// 0.5 MB
  u16* Op  = (u16*)(w + 0 * MB);    // 16 MB, overlaps dead xq..wvb region

  cvt_all<<<14336, 256, 0, stream>>>(query, keys, values, Wq, Wk, Wv, Wo, dist,
                                     xq, xk, xv, wqb, wkb, wvb, wob, Bb);

  dim3 gProj(E_DIM / TN, L_SEQ / TM, 3);
  gemm_bt3b<0><<<gProj, 256, 0, stream>>>(xq, wqb, Qh,
                                          xk, wkb, Kh,
                                          xv, wvb, Vth,
                                          nullptr, L_SEQ, E_DIM, E_DIM);

  dim3 gAttn(L_SEQ / 64, H_HEADS, KSPLIT);
  flash3<<<gAttn, 256, 0, stream>>>(Qh, Kh, Vth, Bb, Op, lp);

  merge_attn<<<(L_SEQ * E_DIM / 4) / 256, 256, 0, stream>>>(Op, lp, AOb);

  dim3 gOut(E_DIM / TN, L_SEQ / TM, 1);
  gemm_bt3b<1><<<gOut, 256, 0, stream>>>(AOb, wob, out,
                                         AOb, wob, out,
                                         AOb, wob, out,
                                         bo, L_SEQ, E_DIM, E_DIM);
}